// Round 8
// baseline (202.693 us; speedup 1.0000x reference)
//
#include <hip/hip_runtime.h>
#include <stdint.h>

#define K_DIM 8192
#define N_DIM 28672

typedef _Float16 half8 __attribute__((ext_vector_type(8)));
typedef _Float16 half2t __attribute__((ext_vector_type(2)));
typedef float f32x16 __attribute__((ext_vector_type(16)));
typedef float f32x4 __attribute__((ext_vector_type(4)));
typedef uint32_t u32x4 __attribute__((ext_vector_type(4)));

// ---- prep: x f32 [32][8192] -> xp f16 [K/8][32][8] in A-fragment slot order
__global__ __launch_bounds__(256) void prep_x(const float* __restrict__ x,
                                              _Float16* __restrict__ xp) {
  int idx = blockIdx.x * 256 + threadIdx.x;  // 32768 = 1024 word-rows * 32 m
  int m  = idx & 31;
  int k8 = idx >> 5;
  const float* p = x + (size_t)m * K_DIM + (size_t)k8 * 8;
  float4 xa = *(const float4*)p;
  float4 xb = *(const float4*)(p + 4);
  half2t p0 = __builtin_bit_cast(half2t, __builtin_amdgcn_cvt_pkrtz(xa.x, xb.x));
  half2t p1 = __builtin_bit_cast(half2t, __builtin_amdgcn_cvt_pkrtz(xa.y, xb.y));
  half2t p2 = __builtin_bit_cast(half2t, __builtin_amdgcn_cvt_pkrtz(xa.z, xb.z));
  half2t p3 = __builtin_bit_cast(half2t, __builtin_amdgcn_cvt_pkrtz(xa.w, xb.w));
  half8 o;
  o[0] = p0[0]; o[1] = p0[1]; o[2] = p1[0]; o[3] = p1[1];
  o[4] = p2[0]; o[5] = p2[1]; o[6] = p3[0]; o[7] = p3[1];
  *(half8*)(xp + ((size_t)k8 * 32 + m) * 8) = o;
}

__global__ __launch_bounds__(256) void zero_out(float4* __restrict__ out) {
  out[(size_t)blockIdx.x * 256 + threadIdx.x] = float4{0.f, 0.f, 0.f, 0.f};
}

// int4 word -> 8 f16 slots [n0,n4,n1,n5,n2,n6,n3,n7], value (n-8)*s (exact add)
static __device__ __forceinline__ half8 dqs(uint32_t w, half2t sh) {
  const uint32_t M4 = 0x000F000Fu, E = 0x64006400u;
  half2t off; off[0] = (_Float16)(-1032.0f); off[1] = (_Float16)(-1032.0f);
  half2t v0 = (__builtin_bit_cast(half2t, ( w        & M4) | E) + off) * sh;
  half2t v1 = (__builtin_bit_cast(half2t, ((w >> 4)  & M4) | E) + off) * sh;
  half2t v2 = (__builtin_bit_cast(half2t, ((w >> 8)  & M4) | E) + off) * sh;
  half2t v3 = (__builtin_bit_cast(half2t, ((w >> 12) & M4) | E) + off) * sh;
  half8 r;
  r[0] = v0[0]; r[1] = v0[1]; r[2] = v1[0]; r[3] = v1[1];
  r[4] = v2[0]; r[5] = v2[1]; r[6] = v3[0]; r[7] = v3[1];
  return r;
}

static __device__ __forceinline__ half2t cvtp(float f) {
  return __builtin_bit_cast(half2t, __builtin_amdgcn_cvt_pkrtz(f, f));
}

// gfx9 s_waitcnt imm: vm[3:0]|[15:14], exp[6:4]=7 (none), lgkm[11:8]=15 (none)
static __device__ __forceinline__ void wvm9() { __builtin_amdgcn_s_waitcnt(0x0F79); }
static __device__ __forceinline__ void wvm6() { __builtin_amdgcn_s_waitcnt(0x0F76); }
static __device__ __forceinline__ void wvm3() { __builtin_amdgcn_s_waitcnt(0x0F73); }
static __device__ __forceinline__ void wvm0() { __builtin_amdgcn_s_waitcnt(0x0F70); }

// r7 pipeline + ONE structural delta: 1KB single-row Q requests.
// All 64 lanes of a Q load read the SAME word-row (lane l -> cols c0+4l..+3,
// one dwordx4 = 1KB contiguous) instead of r7's two 512B half-wave strips.
// Row 2i+1's words then sit in the wrong half-wave for the MFMA B-frag;
// one v_permlane32_swap_b32 per word-pair fixes it AND yields both the
// lo-col (c0+4c+j) and hi-col (c0+128+4c+j) fragments:
//   after swap: lo' = {row2i.lanes0-31, row2i+1.lanes0-31}  -> subtile j
//              hi' = {row2i.lanes32-63, row2i+1.lanes32-63} -> subtile j+4
// Block = 256 cols x K/2 (224 blocks = 112 col-tiles x 2 K-halves; ct and
// ct+112 share an XCD since 112%8==0). 8 waves split the K-half: wave w owns
// 64 word-rows = 4 scale-groups. Each A fragment feeds all 8 subtiles
// (A traffic 114->57MB). 2-way split-K -> unsafeAtomicAdd (7.3MB benign;
// r1's problem was 29MB of 8-way atomics, not atomics per se).
// Pinned queue: 4 pairs x [Qa,Qb,A] = 12 loads in flight; steady vmcnt(9)
// (retire own pair, keep 3 newest); drain 9/6/3/0 over the last 4 steps.
__global__ __launch_bounds__(512, 2) void qgemm(
    const uint32_t* __restrict__ q, const float* __restrict__ scales,
    const float* __restrict__ bias, const _Float16* __restrict__ xp,
    float* __restrict__ out) {
  __shared__ float red[8][16][64];   // 32 KB cross-wave reduce buffer
  const int tid  = threadIdx.x;
  const int w    = tid >> 6;          // 0..7: K-slice owner within the half
  const int lane = tid & 63;
  const int nl   = lane & 31;
  const int bid  = blockIdx.x;
  const int kb   = bid / 112;         // K-half 0..1
  const int ct   = bid - kb * 112;    // 256-col tile 0..111
  const int c0   = ct << 8;
  const int r0w  = (kb << 9) + (w << 6);  // wave's first word-row (64 rows)

  // Preload + convert 32 group scales (4 groups x 8 cols-per-lane-slot).
  half2t sh[4][8];
#pragma unroll
  for (int gg = 0; gg < 4; gg++) {
    int sg = (kb << 5) + (w << 2) + gg;  // global scale-group row
    f32x4 sa = *(const f32x4*)&scales[(size_t)sg * N_DIM + c0 + 4 * nl];
    f32x4 sb = *(const f32x4*)&scales[(size_t)sg * N_DIM + c0 + 128 + 4 * nl];
    sh[gg][0] = cvtp(sa[0]); sh[gg][1] = cvtp(sa[1]);
    sh[gg][2] = cvtp(sa[2]); sh[gg][3] = cvtp(sa[3]);
    sh[gg][4] = cvtp(sb[0]); sh[gg][5] = cvtp(sb[1]);
    sh[gg][6] = cvtp(sb[2]); sh[gg][7] = cvtp(sb[3]);
  }
  wvm0();                             // drain compiler-tracked scale loads
  __builtin_amdgcn_sched_barrier(0);

  const uint32_t RS = (uint32_t)(N_DIM * 4);           // q row stride bytes
  const uint32_t qbase = (uint32_t)(((uint64_t)r0w * N_DIM + c0 + 4 * lane) * 4);
  const int h = lane >> 5;
  const uint32_t abase = (uint32_t)(((r0w + h) * 32 + nl) * 16);

  u32x4 qa[4], qb4[4];   // Q pair ring (rows 2s, 2s+1), 4-pair lead
  f32x4 aA[4];           // A fragment ring

  auto issue = [&](int s) {            // pair s: word-rows r0w+2s, r0w+2s+1
    uint32_t va = qbase + (uint32_t)(2 * s) * RS;
    asm volatile("global_load_dwordx4 %0, %1, %2"
                 : "=v"(qa[s & 3]) : "v"(va), "s"(q));
    asm volatile("global_load_dwordx4 %0, %1, %2"
                 : "=v"(qb4[s & 3]) : "v"(va + RS), "s"(q));
    uint32_t vA = abase + (uint32_t)(2 * s) * 512;     // xp: 512B per word-row
    asm volatile("global_load_dwordx4 %0, %1, %2"
                 : "=v"(aA[s & 3]) : "v"(vA), "s"(xp));
  };

  f32x16 acc0, acc1, acc2, acc3, acc4, acc5, acc6, acc7;
#pragma unroll
  for (int j = 0; j < 16; j++) {
    acc0[j] = 0.f; acc1[j] = 0.f; acc2[j] = 0.f; acc3[j] = 0.f;
    acc4[j] = 0.f; acc5[j] = 0.f; acc6[j] = 0.f; acc7[j] = 0.f;
  }

  issue(0); issue(1); issue(2); issue(3);   // 12 loads in flight

#define SUB(J_, ACCL_, ACCH_)                                                 \
  do {                                                                        \
    uint32_t lo = qa[t][J_], hi = qb4[t][J_];                                 \
    asm volatile("v_permlane32_swap_b32 %0, %1" : "+v"(lo), "+v"(hi));        \
    ACCL_ = __builtin_amdgcn_mfma_f32_32x32x16_f16(af, dqs(lo, sh[gg][J_]),   \
                                                   ACCL_, 0, 0, 0);           \
    ACCH_ = __builtin_amdgcn_mfma_f32_32x32x16_f16(af, dqs(hi, sh[gg][J_+4]), \
                                                   ACCH_, 0, 0, 0);           \
  } while (0)

#pragma unroll
  for (int s = 0; s < 32; ++s) {
    // retire pair s; keep the 3 newest pairs (9 loads) in flight
    if (s <= 27) wvm9();
    else if (s == 28) wvm9();
    else if (s == 29) wvm6();
    else if (s == 30) wvm3();
    else wvm0();
    __builtin_amdgcn_sched_barrier(0);   // rule #18: no consumer hoists above
    const int t = s & 3, gg = s >> 3;
    half8 af = __builtin_bit_cast(half8, aA[t]);
    SUB(0, acc0, acc4);
    SUB(1, acc1, acc5);
    SUB(2, acc2, acc6);
    SUB(3, acc3, acc7);
    if (s + 4 < 32) issue(s + 4);
  }
#undef SUB

  // ---- epilogue: per subtile J, cross-wave K-reduce in LDS, then one
  // atomicAdd per element (2 K-half contenders). Physical col of subtile J:
  // c0 + 128*(J>>2) + 4*(ln&31) + (J&3); row = (reg&3)+8*(reg>>2)+4*(ln>>5).
#pragma unroll
  for (int J = 0; J < 8; J++) {
    f32x16 accJ = (J == 0) ? acc0 : (J == 1) ? acc1 : (J == 2) ? acc2 :
                  (J == 3) ? acc3 : (J == 4) ? acc4 : (J == 5) ? acc5 :
                  (J == 6) ? acc6 : acc7;
#pragma unroll
    for (int r = 0; r < 16; r++) red[w][r][lane] = accJ[r];
    __syncthreads();
#pragma unroll
    for (int s = 0; s < 2; s++) {
      int p   = tid + s * 512;
      int reg = p >> 6, ln = p & 63;
      float v = 0.f;
#pragma unroll
      for (int u = 0; u < 8; u++) v += red[u][reg][ln];
      int row = (reg & 3) + ((reg >> 2) << 3) + ((ln >> 5) << 2);
      int col = c0 + ((J >> 2) << 7) + 4 * (ln & 31) + (J & 3);
      float add = v + ((kb == 0) ? bias[col] : 0.f);
      unsafeAtomicAdd(&out[(size_t)row * N_DIM + col], add);
    }
    __syncthreads();   // red free before next subtile overwrites it
  }
}

extern "C" void kernel_launch(void* const* d_in, const int* in_sizes, int n_in,
                              void* d_out, int out_size, void* d_ws, size_t ws_size,
                              hipStream_t stream) {
  const float*    xf      = (const float*)d_in[0];
  const uint32_t* qweight = (const uint32_t*)d_in[1];
  const float*    scales  = (const float*)d_in[2];
  const float*    bias    = (const float*)d_in[3];
  float*          out     = (float*)d_out;
  _Float16*       xp      = (_Float16*)d_ws;   // 512 KB scratch

  zero_out<<<dim3(896), dim3(256), 0, stream>>>((float4*)out);
  prep_x<<<dim3(128), dim3(256), 0, stream>>>(xf, xp);
  qgemm<<<dim3(224), dim3(512), 0, stream>>>(qweight, scales, bias, xp, out);
}

// Round 9
// 189.397 us; speedup vs baseline: 1.0702x; 1.0702x over previous
//
#include <hip/hip_runtime.h>
#include <stdint.h>

#define K_DIM 8192
#define N_DIM 28672
#define NG    8    // scale-groups per wave (8 waves split K: 1024 k each)

typedef _Float16 half8 __attribute__((ext_vector_type(8)));
typedef _Float16 half2t __attribute__((ext_vector_type(2)));
typedef float f32x16 __attribute__((ext_vector_type(16)));
typedef float f32x4 __attribute__((ext_vector_type(4)));
typedef uint32_t u32x4 __attribute__((ext_vector_type(4)));

// ---- prep: x f32 [32][8192] -> xp f16 [K/8][32][8] in A-fragment slot order
__global__ __launch_bounds__(256) void prep_x(const float* __restrict__ x,
                                              _Float16* __restrict__ xp) {
  int idx = blockIdx.x * 256 + threadIdx.x;  // 32768 = 1024 word-rows * 32 m
  int m  = idx & 31;
  int k8 = idx >> 5;
  const float* p = x + (size_t)m * K_DIM + (size_t)k8 * 8;
  float4 xa = *(const float4*)p;
  float4 xb = *(const float4*)(p + 4);
  half2t p0 = __builtin_bit_cast(half2t, __builtin_amdgcn_cvt_pkrtz(xa.x, xb.x));
  half2t p1 = __builtin_bit_cast(half2t, __builtin_amdgcn_cvt_pkrtz(xa.y, xb.y));
  half2t p2 = __builtin_bit_cast(half2t, __builtin_amdgcn_cvt_pkrtz(xa.z, xb.z));
  half2t p3 = __builtin_bit_cast(half2t, __builtin_amdgcn_cvt_pkrtz(xa.w, xb.w));
  half8 o;
  o[0] = p0[0]; o[1] = p0[1]; o[2] = p1[0]; o[3] = p1[1];
  o[4] = p2[0]; o[5] = p2[1]; o[6] = p3[0]; o[7] = p3[1];
  *(half8*)(xp + ((size_t)k8 * 32 + m) * 8) = o;
}

// int4 word -> 8 f16 slots [n0,n4,n1,n5,n2,n6,n3,n7], value (n-8)*s (exact add)
static __device__ __forceinline__ half8 dqs(uint32_t w, half2t sh) {
  const uint32_t M4 = 0x000F000Fu, E = 0x64006400u;
  half2t off; off[0] = (_Float16)(-1032.0f); off[1] = (_Float16)(-1032.0f);
  half2t v0 = (__builtin_bit_cast(half2t, ( w        & M4) | E) + off) * sh;
  half2t v1 = (__builtin_bit_cast(half2t, ((w >> 4)  & M4) | E) + off) * sh;
  half2t v2 = (__builtin_bit_cast(half2t, ((w >> 8)  & M4) | E) + off) * sh;
  half2t v3 = (__builtin_bit_cast(half2t, ((w >> 12) & M4) | E) + off) * sh;
  half8 r;
  r[0] = v0[0]; r[1] = v0[1]; r[2] = v1[0]; r[3] = v1[1];
  r[4] = v2[0]; r[5] = v2[1]; r[6] = v3[0]; r[7] = v3[1];
  return r;
}

static __device__ __forceinline__ half2t cvtp(float f) {
  return __builtin_bit_cast(half2t, __builtin_amdgcn_cvt_pkrtz(f, f));
}

// gfx9 s_waitcnt imm: vm[3:0]|[15:14], exp[6:4]=7 (none), lgkm[11:8]=15 (none)
static __device__ __forceinline__ void wvm16() { __builtin_amdgcn_s_waitcnt(0x4F70); }
static __device__ __forceinline__ void wvm8()  { __builtin_amdgcn_s_waitcnt(0x0F78); }
static __device__ __forceinline__ void wvm0()  { __builtin_amdgcn_s_waitcnt(0x0F70); }

// r7 skeleton (best-known, ~48us qgemm) + ONE delta: Q prefetch depth 2->3
// (triple-buffered qr, 2-step ~3.2k-cy lead) to cover loaded-HBM latency.
// A-prefetch becomes a single batched issue at step end (A is L2-hot, 512KB
// xp; 1-step ~1.6k-cy lead suffices) so the in-order vmcnt queue stays
// analyzable: end of step g issues [A(g+1), Q(g+3)].
// Steady outstanding at step-g wait: [Q(g+1), A(g), Q(g+2)] = 24 loads ->
// retire through A(g) with vmcnt(8) (keep Q(g+2)'s 8 newest). g=0: queue
// [Q0,A0,Q1,Q2] -> vmcnt(16). g>=6: tail, vmcnt(0). Never drain mid-loop.
// Block = 128 cols x full K (224 blocks). 8 waves split K: wave w owns
// word-rows [w*128, w*128+128) = 8 scale-groups. Lane (h,nl) loads Q cols
// {c0+4nl..+3} of row 16g+2i+h in one dwordx4 (512B per 32-lane half).
// Word j feeds subtile j, physical col c0+4*nl+j (relabel applied at store).
// Each A fragment feeds all 4 subtiles. Scales preloaded to registers.
// No atomics; store-once epilogue (r8 post-mortem: multi-pass atomic
// epilogue re-dirties output lines ~8x -> 29MB writes. Keep stores).
__global__ __launch_bounds__(512, 2) void qgemm(
    const uint32_t* __restrict__ q, const float* __restrict__ scales,
    const float* __restrict__ bias, const _Float16* __restrict__ xp,
    float* __restrict__ out) {
  __shared__ float red[8][16][64];   // 32 KB cross-wave reduce buffer
  const int tid  = threadIdx.x;
  const int w    = tid >> 6;         // 0..7: K-slice owner
  const int lane = tid & 63;
  const int h    = lane >> 5;
  const int nl   = lane & 31;
  const int c0   = blockIdx.x << 7;  // 128-col tile
  const int wr0  = w << 7;           // wave's first word-row

  // Preload + convert the 32 group scales (8 groups x 4 cols per lane),
  // one coalesced f32x4 per group.
  half2t sh[8][4];
#pragma unroll
  for (int g = 0; g < NG; g++) {
    f32x4 sv = *(const f32x4*)&scales[(size_t)(w * NG + g) * N_DIM + c0 + 4 * nl];
    sh[g][0] = cvtp(sv[0]); sh[g][1] = cvtp(sv[1]);
    sh[g][2] = cvtp(sv[2]); sh[g][3] = cvtp(sv[3]);
  }
  wvm0();                             // drain compiler-tracked scale loads
  __builtin_amdgcn_sched_barrier(0);

  // 32-bit voffsets (arrays < 4 GB)
  const uint32_t qb = (uint32_t)((((uint64_t)(wr0 + h)) * N_DIM + c0 + 4 * nl) * 4);
  const uint32_t ab = (uint32_t)(((wr0 + h) * 32 + nl) * 16);

  u32x4 qr[3][8];   // Q word quads, 3-deep ring (2-step lead)
  f32x4 aA[8];      // A fragments (half8 bits), single buffer, batch reissue

  auto qload = [&](int g) {
#pragma unroll
    for (int i = 0; i < 8; i++) {
      uint32_t vo = qb + (uint32_t)(g * 16 + 2 * i) * (uint32_t)(N_DIM * 4);
      asm volatile("global_load_dwordx4 %0, %1, %2"
                   : "=v"(qr[g % 3][i]) : "v"(vo), "s"(q));
    }
  };
  auto aloadAll = [&](int g) {
#pragma unroll
    for (int i = 0; i < 8; i++) {
      uint32_t vo = ab + (uint32_t)(g * 8192 + i * 1024);
      asm volatile("global_load_dwordx4 %0, %1, %2"
                   : "=v"(aA[i]) : "v"(vo), "s"(xp));
    }
  };

  f32x16 acc0, acc1, acc2, acc3;
#pragma unroll
  for (int j = 0; j < 16; j++) { acc0[j] = 0.f; acc1[j] = 0.f; acc2[j] = 0.f; acc3[j] = 0.f; }

  // prologue queue: [Q0(8), A0(8), Q1(8), Q2(8)]
  qload(0);
  aloadAll(0);
  qload(1);
  qload(2);

#pragma unroll
  for (int g = 0; g < NG; g++) {
    // g=0: retire Q0+A0, keep Q1,Q2 (16). steady: retire through A(g),
    // keep Q(g+2) (8). tail g>=6: drain (A(g) is newest in queue there).
    if (g == 0) wvm16();
    else if (g <= 5) wvm8();
    else wvm0();
    __builtin_amdgcn_sched_barrier(0);   // rule #18: no consumer hoists above
    half2t s0 = sh[g][0], s1 = sh[g][1], s2 = sh[g][2], s3 = sh[g][3];
#pragma unroll
    for (int i = 0; i < 8; i++) {
      half8 af = __builtin_bit_cast(half8, aA[i]);
      u32x4 qw = qr[g % 3][i];
      acc0 = __builtin_amdgcn_mfma_f32_32x32x16_f16(af, dqs(qw[0], s0), acc0, 0, 0, 0);
      acc1 = __builtin_amdgcn_mfma_f32_32x32x16_f16(af, dqs(qw[1], s1), acc1, 0, 0, 0);
      acc2 = __builtin_amdgcn_mfma_f32_32x32x16_f16(af, dqs(qw[2], s2), acc2, 0, 0, 0);
      acc3 = __builtin_amdgcn_mfma_f32_32x32x16_f16(af, dqs(qw[3], s3), acc3, 0, 0, 0);
    }
    // issue order matters for in-order vmcnt: A(g+1) BEFORE Q(g+3).
    if (g + 1 < NG) aloadAll(g + 1);   // WAR on aA: all reads above are done
    if (g + 3 < NG) qload(g + 3);
  }

  // ---- epilogue: cross-wave K-reduce per subtile; physical col = c0+4*nl+J.
#pragma unroll
  for (int J = 0; J < 4; J++) {
    f32x16 accJ = (J == 0) ? acc0 : (J == 1) ? acc1 : (J == 2) ? acc2 : acc3;
#pragma unroll
    for (int r = 0; r < 16; r++) red[w][r][lane] = accJ[r];
    __syncthreads();
#pragma unroll
    for (int s = 0; s < 2; s++) {
      int p   = tid + s * 512;
      int reg = p >> 6, ln = p & 63;
      float v = 0.f;
#pragma unroll
      for (int u = 0; u < 8; u++) v += red[u][reg][ln];
      int row = (reg & 3) + ((reg >> 2) << 3) + ((ln >> 5) << 2);
      int col = c0 + 4 * (ln & 31) + J;
      out[(size_t)row * N_DIM + col] = v + bias[col];
    }
    __syncthreads();   // red free before next subtile overwrites it
  }
}

extern "C" void kernel_launch(void* const* d_in, const int* in_sizes, int n_in,
                              void* d_out, int out_size, void* d_ws, size_t ws_size,
                              hipStream_t stream) {
  const float*    xf      = (const float*)d_in[0];
  const uint32_t* qweight = (const uint32_t*)d_in[1];
  const float*    scales  = (const float*)d_in[2];
  const float*    bias    = (const float*)d_in[3];
  float*          out     = (float*)d_out;
  _Float16*       xp      = (_Float16*)d_ws;   // 512 KB scratch

  prep_x<<<dim3(128), dim3(256), 0, stream>>>(xf, xp);
  qgemm<<<dim3(N_DIM / 128), dim3(512), 0, stream>>>(qweight, scales, bias, xp, out);
}